// Round 1
// baseline (2743.684 us; speedup 1.0000x reference)
//
#include <hip/hip_runtime.h>
#include <hip/hip_bf16.h>
#include <cstdint>
#include <cstddef>

// BiLSTM tagger, f32 end-to-end.
// Structure: embed -> [GEMM pre -> multi-CU LSTM scan] x2 -> 4 MLP GEMMs -> bilinear (2 GEMMs).
// Scan: 8 blocks (2 dirs x 4 parts). Each block holds 200 rows of Whh (100 f32/thread) in VGPRs,
// exchanges its 50-element h-slice through L2 each step with agent-scope atomics + epoch flags.

#define TSEQ 512
#define HDIR 200
#define INSZ 400
#define G4   800
#define JS   50      // HDIR/4
#define ROWS_PB 200  // G4/4

// ---------------- embedding ----------------
__global__ void k_embed(const float* __restrict__ we, const float* __restrict__ pe,
                        const int* __restrict__ wi, const int* __restrict__ pi,
                        float* __restrict__ x) {
  int t = blockIdx.x;
  int w = wi[t], p = pi[t];
  const float* wrow = we + (size_t)w * 300;
  const float* prow = pe + (size_t)p * 100;
  for (int j = threadIdx.x; j < INSZ; j += blockDim.x)
    x[(size_t)t * INSZ + j] = (j < 300) ? wrow[j] : prow[j - 300];
}

__global__ void k_add(const float* __restrict__ a, const float* __restrict__ b,
                      float* __restrict__ o, int n) {
  int i = blockIdx.x * blockDim.x + threadIdx.x;
  if (i < n) o[i] = a[i] + b[i];
}

// ---------------- GEMM: C[n][m] = act(A[n][k] * B[m][k]^T + bias) ----------------
// n must be a multiple of 64 (always 512 here); m may be ragged (col-guarded); k % 16 == 0.
__global__ __launch_bounds__(256) void k_gemm_bt(
    const float* __restrict__ A, const float* __restrict__ B,
    const float* __restrict__ bias, float* __restrict__ C,
    int n, int m, int k, int bias_mode, int do_relu)
{
  __shared__ float As[16][68];
  __shared__ float Bs[16][68];
  const int tid = threadIdx.x;
  const int tx = tid & 15, ty = tid >> 4;
  const int row0 = blockIdx.y << 6, col0 = blockIdx.x << 6;
  const int lr = tid >> 2;          // 0..63
  const int kq = (tid & 3) << 2;    // 0,4,8,12
  float acc[4][4] = {};

  for (int ks = 0; ks < k; ks += 16) {
    float4 a4 = *(const float4*)(A + (size_t)(row0 + lr) * k + ks + kq);
    float4 b4 = make_float4(0.f, 0.f, 0.f, 0.f);
    if (col0 + lr < m)
      b4 = *(const float4*)(B + (size_t)(col0 + lr) * k + ks + kq);
    As[kq + 0][lr] = a4.x; As[kq + 1][lr] = a4.y; As[kq + 2][lr] = a4.z; As[kq + 3][lr] = a4.w;
    Bs[kq + 0][lr] = b4.x; Bs[kq + 1][lr] = b4.y; Bs[kq + 2][lr] = b4.z; Bs[kq + 3][lr] = b4.w;
    __syncthreads();
#pragma unroll
    for (int kk = 0; kk < 16; ++kk) {
      const float4 av = *(const float4*)&As[kk][ty << 2];
      const float4 bv = *(const float4*)&Bs[kk][tx << 2];
      const float a_[4] = {av.x, av.y, av.z, av.w};
      const float b_[4] = {bv.x, bv.y, bv.z, bv.w};
#pragma unroll
      for (int i = 0; i < 4; ++i)
#pragma unroll
        for (int j = 0; j < 4; ++j)
          acc[i][j] += a_[i] * b_[j];
    }
    __syncthreads();
  }

#pragma unroll
  for (int i = 0; i < 4; ++i) {
    const int r = row0 + (ty << 2) + i;
#pragma unroll
    for (int j = 0; j < 4; ++j) {
      const int c = col0 + (tx << 2) + j;
      if (c < m) {
        float v = acc[i][j];
        if (bias_mode == 1) v += bias[c];
        else if (bias_mode == 2) v += bias[0];
        if (do_relu) v = fmaxf(v, 0.f);
        C[(size_t)r * m + c] = v;
      }
    }
  }
}

// ---------------- LSTM scan ----------------
// grid = 8 blocks: dir = bid>>2, part p = bid&3. 512 threads/block.
// Thread (rr = tid>>1, u = tid&1): row rr of this block's 200 gate rows, k-half u.
// Block p owns hidden slice j in [p*50, p*50+50): gate rows {g*200 + p*50 + q}.
__global__ __launch_bounds__(512) void k_scan(
    const float* __restrict__ Whh,   // [2][2][800][200]
    const float* __restrict__ pre,   // [512][1600]
    float* __restrict__ hs,          // [512][400] output (concat fwd|bwd)
    float* hbuf,                     // [2 parity][2 dir][256]
    int* epochs,                     // [2 dir][4 part], zeroed by host
    int layer)
{
  const int bid = blockIdx.x;
  const int dir = bid >> 2;
  const int p = bid & 3;
  const int tid = threadIdx.x;
  const int rr = tid >> 1;
  const int u = tid & 1;
  const bool act = (rr < ROWS_PB);
  const int gate = rr / JS;          // 0..3 (i,f,g,o)
  const int q = rr - gate * JS;      // 0..49
  const int grow = gate * HDIR + p * JS + q;

  __shared__ float h_lds[HDIR];
  __shared__ float g_lds[ROWS_PB];   // [gate*50 + q]

  float4 w4[25];
  if (act) {
    const float* wrow = Whh + ((size_t)(layer * 2 + dir) * G4 + grow) * HDIR + u * 100;
#pragma unroll
    for (int i = 0; i < 25; ++i) w4[i] = *(const float4*)(wrow + i * 4);
  } else {
#pragma unroll
    for (int i = 0; i < 25; ++i) w4[i] = make_float4(0.f, 0.f, 0.f, 0.f);
  }

  for (int i = tid; i < HDIR; i += 512) h_lds[i] = 0.f;
  float c_state = 0.f;               // valid for tid < JS
  int* eps = epochs + dir * 4;
  __syncthreads();

  for (int t = 0; t < TSEQ; ++t) {
    const int inrow = dir ? (TSEQ - 1 - t) : t;
    const int wb = (((t + 1) & 1) * 2 + dir) * 256;   // hbuf slot for h_{t+1}

    if (act) {
      float preval = 0.f;
      if (u == 0) preval = pre[(size_t)inrow * 1600 + dir * G4 + grow];
      float accd = 0.f;
      const float* hb = h_lds + u * 100;
#pragma unroll
      for (int i = 0; i < 25; ++i) {
        const float4 hv = *(const float4*)(hb + i * 4);
        accd += w4[i].x * hv.x + w4[i].y * hv.y + w4[i].z * hv.z + w4[i].w * hv.w;
      }
      accd += __shfl_xor(accd, 1);   // combine the two k-halves (lane pairs)
      if (u == 0) g_lds[rr] = accd + preval;
    }
    __syncthreads();

    if (tid < JS) {
      const float gi = g_lds[tid];
      const float gf = g_lds[JS + tid];
      const float gg = g_lds[2 * JS + tid];
      const float go = g_lds[3 * JS + tid];
      const float si = 1.f / (1.f + __expf(-gi));
      const float sf = 1.f / (1.f + __expf(-gf));
      const float so = 1.f / (1.f + __expf(-go));
      const float tg = 2.f / (1.f + __expf(-2.f * gg)) - 1.f;
      c_state = sf * c_state + si * tg;
      const float tc = 2.f / (1.f + __expf(-2.f * c_state)) - 1.f;
      const float hv = so * tc;
      hs[(size_t)inrow * INSZ + dir * HDIR + p * JS + tid] = hv;
      if (t != TSEQ - 1)
        __hip_atomic_store(&hbuf[wb + p * JS + tid], hv,
                           __ATOMIC_RELAXED, __HIP_MEMORY_SCOPE_AGENT);
    }
    if (t == TSEQ - 1) break;

    __syncthreads();   // drains vmcnt: hbuf slice visible before epoch release
    if (tid == 0)
      __hip_atomic_store(&eps[p], t + 1, __ATOMIC_RELEASE, __HIP_MEMORY_SCOPE_AGENT);
    if (tid >= 64 && tid < 68) {
      while (__hip_atomic_load(&eps[tid - 64], __ATOMIC_ACQUIRE,
                               __HIP_MEMORY_SCOPE_AGENT) <= t) {}
    }
    __syncthreads();

    if (tid < JS) {    // gather full h_{t+1} (L1-bypassing loads) into LDS
      const float a0 = __hip_atomic_load(&hbuf[wb + tid * 4 + 0], __ATOMIC_RELAXED, __HIP_MEMORY_SCOPE_AGENT);
      const float a1 = __hip_atomic_load(&hbuf[wb + tid * 4 + 1], __ATOMIC_RELAXED, __HIP_MEMORY_SCOPE_AGENT);
      const float a2 = __hip_atomic_load(&hbuf[wb + tid * 4 + 2], __ATOMIC_RELAXED, __HIP_MEMORY_SCOPE_AGENT);
      const float a3 = __hip_atomic_load(&hbuf[wb + tid * 4 + 3], __ATOMIC_RELAXED, __HIP_MEMORY_SCOPE_AGENT);
      h_lds[tid * 4 + 0] = a0; h_lds[tid * 4 + 1] = a1;
      h_lds[tid * 4 + 2] = a2; h_lds[tid * 4 + 3] = a3;
    }
    __syncthreads();
  }
}

// ---------------- host ----------------
extern "C" void kernel_launch(void* const* d_in, const int* in_sizes, int n_in,
                              void* d_out, int out_size, void* d_ws, size_t ws_size,
                              hipStream_t stream)
{
  const float* we   = (const float*)d_in[0];
  const float* pe   = (const float*)d_in[1];
  const float* Wih  = (const float*)d_in[2];
  const float* Whh  = (const float*)d_in[3];
  const float* bih  = (const float*)d_in[4];
  const float* bhh  = (const float*)d_in[5];
  const float* W_h1 = (const float*)d_in[6];
  const float* b_h1 = (const float*)d_in[7];
  const float* W_h2 = (const float*)d_in[8];
  const float* b_h2 = (const float*)d_in[9];
  const float* W_d1 = (const float*)d_in[10];
  const float* b_d1 = (const float*)d_in[11];
  const float* W_d2 = (const float*)d_in[12];
  const float* b_d2 = (const float*)d_in[13];
  const float* W_bi = (const float*)d_in[14];
  const float* b_bi = (const float*)d_in[15];
  const int*   wi   = (const int*)d_in[16];
  const int*   pi   = (const int*)d_in[17];
  float* out = (float*)d_out;

  float* ws = (float*)d_ws;             // ~8.2 MB of f32 used
  float* x0   = ws;                     // 512*400
  float* pre  = ws + 204800;            // 512*1600
  float* h1   = ws + 1024000;           // 512*400
  float* h2   = ws + 1228800;           // 512*400
  float* m1   = ws + 1433600;           // 512*400 scratch
  float* m2   = ws + 1638400;           // 512*400 (head)
  float* m3   = ws + 1843200;           // 512*400 (dep)
  float* bsum = ws + 2048000;           // 3200
  float* hbuf = ws + 2051200;           // 1024
  int* epochs = (int*)(ws + 2052224);   // 16 ints

  hipMemsetAsync(epochs, 0, 16 * sizeof(int), stream);
  k_embed<<<TSEQ, 128, 0, stream>>>(we, pe, wi, pi, x0);
  k_add<<<(3200 + 255) / 256, 256, 0, stream>>>(bih, bhh, bsum, 3200);

  // layer 0: pre = x0 @ Wih[0]^T + (bih+bhh)[0]  -> [512][1600] (dir0 | dir1)
  k_gemm_bt<<<dim3(25, 8), 256, 0, stream>>>(x0, Wih, bsum, pre, 512, 1600, 400, 1, 0);
  k_scan<<<8, 512, 0, stream>>>(Whh, pre, h1, hbuf, epochs, 0);

  // layer 1
  k_gemm_bt<<<dim3(25, 8), 256, 0, stream>>>(h1, Wih + 1600 * 400, bsum + 1600, pre, 512, 1600, 400, 1, 0);
  k_scan<<<8, 512, 0, stream>>>(Whh, pre, h2, hbuf, epochs + 8, 1);

  // head = relu(relu(h2 W_h1^T + b_h1) W_h2^T + b_h2)
  k_gemm_bt<<<dim3(7, 8), 256, 0, stream>>>(h2, W_h1, b_h1, m1, 512, 400, 400, 1, 1);
  k_gemm_bt<<<dim3(7, 8), 256, 0, stream>>>(m1, W_h2, b_h2, m2, 512, 400, 400, 1, 1);
  // dep
  k_gemm_bt<<<dim3(7, 8), 256, 0, stream>>>(h2, W_d1, b_d1, m1, 512, 400, 400, 1, 1);
  k_gemm_bt<<<dim3(7, 8), 256, 0, stream>>>(m1, W_d2, b_d2, m3, 512, 400, 400, 1, 1);

  // bilinear: t1[j][d] = sum_e dep[j][e] * W_bi[d][e]  (A.B^T with B=W_bi)
  k_gemm_bt<<<dim3(7, 8), 256, 0, stream>>>(m3, W_bi, nullptr, m1, 512, 400, 400, 0, 0);
  // out[i][j] = sum_d head[i][d] * t1[j][d] + b_bi
  k_gemm_bt<<<dim3(8, 8), 256, 0, stream>>>(m2, m1, b_bi, out, 512, 512, 400, 2, 0);
}